// Round 2
// 279.723 us; speedup vs baseline: 1.0502x; 1.0502x over previous
//
#include <hip/hip_runtime.h>
#include <cstdint>

// R8 = R7 resubmit (round 1 failed with a container-level infra error; kernel
// audit found no mechanism: LDS 70.4KB static is legal on gfx950 (HK uses
// 128KB static in plain HIP), barriers uniform, dbuf race-free, no
// graph-capture violations).
//
// R7: single fused kernel. 512 blocks (one per branch) x 512 threads (8 waves).
// rocprof (R6) showed the timed window dominated by fixed harness poison
// fills (~78us each @86% HBM peak); controllable slice = gemm (HBM floor
// 268MB ~= 40us) + ws round-trip (16.8MB) + epilogue dispatch + graph gap.
// Fusing kWTA into the GEMM kernel removes the second dispatch, the gap,
// and all ws traffic. Residency grid-capped at 2 blocks/CU (16 waves/CU);
// co-resident block covers barrier drains; 32KB/block of in-flight NT
// prefetch covers HBM latency. CHUNK=128 halves barrier count to 16.

typedef float vf4 __attribute__((ext_vector_type(4)));
typedef float vf2 __attribute__((ext_vector_type(2)));

#define RFN 512
#define TN  32
#define KN  32
#define LN  2048
#define CHUNK 128
#define NITER (LN / CHUNK)   // 16

__global__ __launch_bounds__(512, 4) void column1_fused(
    const float* __restrict__ rec,   // (T=32, C=1, RF=512, L=2048)
    const float* __restrict__ wgt,   // (RF=512, K=32, C=1, L=2048)
    float* __restrict__ out)         // (T=32, 1, K=32, RF=512)
{
    __shared__ __align__(16) float lds[2 * 64 * CHUNK];  // 64 KB dbuf; tail reuses as red
    __shared__ float thr_s[32 * 33];
    __shared__ float nspk_s[32], vals_s[32], cand_s[32], tot_s[32], mask_s[32];

    const int r    = blockIdx.x;     // branch
    const int tid  = threadIdx.x;
    const int lane = tid & 63;
    const int wv   = tid >> 6;       // wave 0..7: splits chunk's 32 quads 8-ways
    const int tg   = lane >> 3;      // 0..7 : owns t in {tg, tg+8, tg+16, tg+24}
    const int kg   = lane & 7;       // 0..7 : owns k in {kg, kg+8, kg+16, kg+24}

    // ---- staging: 4 vf4/thread; rows r0+16s (0..31 rec-t, 32..63 wgt-k), quad c4
    const int c4 = tid & 31;         // quad within 128 floats
    const int r0 = tid >> 5;         // 0..15
    const float* gsrc[4];
    int ldoff[4];
#pragma unroll
    for (int s = 0; s < 4; ++s) {
        const int row = r0 + 16 * s;                // 0..63
        const float* g;
        if (row < 32) g = rec + ((size_t)(row * RFN + r)) * LN + (c4 << 2);
        else          g = wgt + ((size_t)(r * KN + (row - 32))) * LN + (c4 << 2);
        gsrc[s]  = g;
        // XOR swizzle: quad c4 stored at c4 ^ (row&31) -> conflict-free b128 reads, no pad
        ldoff[s] = row * CHUNK + ((c4 ^ (row & 31)) << 2);
    }

    vf4 stage[4];
#pragma unroll
    for (int s = 0; s < 4; ++s)
        stage[s] = __builtin_nontemporal_load((const vf4*)gsrc[s]);  // NT: no dirty-L3 evict storm (R5)

    float acc[4][4];
#pragma unroll
    for (int jt = 0; jt < 4; ++jt)
#pragma unroll
        for (int jk = 0; jk < 4; ++jk) acc[jt][jk] = 0.0f;

    for (int it = 0; it < NITER; ++it) {
        float* buf = lds + (it & 1) * (64 * CHUNK);
#pragma unroll
        for (int s = 0; s < 4; ++s) *(vf4*)(buf + ldoff[s]) = stage[s];
        __syncthreads();                             // double-buffer: one barrier/chunk
        if (it + 1 < NITER) {
#pragma unroll
            for (int s = 0; s < 4; ++s) {
                gsrc[s] += CHUNK;
                stage[s] = __builtin_nontemporal_load((const vf4*)gsrc[s]);
            }
        }
        const float* rs  = buf;
        const float* wsh = buf + 32 * CHUNK;
#pragma unroll
        for (int q = 0; q < 4; ++q) {
            const int qg = (wv << 2) + q;            // this wave's l-quad (0..31)
            vf4 a[4], b[4];
#pragma unroll
            for (int j = 0; j < 4; ++j) {
                const int row = tg + 8 * j;
                a[j] = *(const vf4*)(rs + row * CHUNK + ((qg ^ (row & 31)) << 2));
            }
#pragma unroll
            for (int j = 0; j < 4; ++j) {
                const int row = kg + 8 * j;          // stored at (32+row); (32+row)&31 == row
                b[j] = *(const vf4*)(wsh + row * CHUNK + ((qg ^ (row & 31)) << 2));
            }
#pragma unroll
            for (int jt = 0; jt < 4; ++jt)
#pragma unroll
                for (int jk = 0; jk < 4; ++jk) {
                    float v0 = fmaf(a[jt].x, b[jk].x, acc[jt][jk]);
                    v0 = fmaf(a[jt].y, b[jk].y, v0);
                    v0 = fmaf(a[jt].z, b[jk].z, v0);
                    acc[jt][jk] = fmaf(a[jt].w, b[jk].w, v0);
                }
        }
    }

    __syncthreads();   // all waves done reading buf1 before red overwrites buf0 region

    // ---- cross-wave reduction: 8 sets x 1024 floats = 32 KB into the dbuf region
    float* red = lds;
#pragma unroll
    for (int jt = 0; jt < 4; ++jt)
#pragma unroll
        for (int jk = 0; jk < 4; ++jk)
            red[(wv << 10) + (tg + 8 * jt) * 32 + (kg + 8 * jk)] = acc[jt][jk];
    __syncthreads();

    // ---- each thread sums 2 outputs over the 8 wave-sets, thresholds into thr_s
    const int o2 = tid << 1;                         // 0..1022, flat (t,k) = o2>>5, o2&31
    float pv0 = 0.0f, pv1 = 0.0f;
#pragma unroll
    for (int s = 0; s < 8; ++s) {
        vf2 p = *(const vf2*)(red + (s << 10) + o2);
        pv0 += p.x; pv1 += p.y;
    }
    {
        const float th0 = (pv0 > 20.0f) ? pv0 : 0.0f;  // sf.fire: strictly greater
        const float th1 = (pv1 > 20.0f) ? pv1 : 0.0f;
        thr_s[(o2 >> 5) * 33 + (o2 & 31)]             = th0;
        thr_s[((o2 + 1) >> 5) * 33 + ((o2 + 1) & 31)] = th1;
    }
    __syncthreads();

    // ---- kWTA (verified logic from the passing R6 epilogue, unchanged)
    if (tid < 32) {
        const int k = tid;
        int ns = 0;
        for (int t = 0; t < 32; ++t) ns += (thr_s[t * 33 + k] > 0.0f) ? 1 : 0;
        int first = 32 - ns; if (first > 31) first = 31;   // clip(T - nspk, 0, T-1)
        const float vf = thr_s[first * 33 + k];
        nspk_s[k] = (float)ns;
        vals_s[k] = vf;
        cand_s[k] = (ns > 0) ? vf : 0.0f;                  // max_t spikes*vals per k
        mask_s[k] = 0.0f;
    }
    __syncthreads();

    if (tid == 0) {
        float vm = 0.0f;
        for (int k = 0; k < 32; ++k) vm = fmaxf(vm, cand_s[k]);
        const float v = vm * 32.0f;                        // trunc.max() * T
        for (int k = 0; k < 32; ++k) tot_s[k] = nspk_s[k] * (vals_s[k] + v);
        // top-4, ties -> lower index (matches lax.top_k); winner valid iff total != 0
        for (int sel = 0; sel < 4; ++sel) {
            int best = 0; float bv = -1.0f;
            for (int k = 0; k < 32; ++k) {
                const float tv = tot_s[k];
                if (tv > bv) { bv = tv; best = k; }
            }
            if (bv > 0.0f) mask_s[best] = 1.0f;
            tot_s[best] = -1.0f;
        }
    }
    __syncthreads();

#pragma unroll
    for (int e = 0; e < 2; ++e) {
        const int oo = o2 + e;
        const int t = oo >> 5, k = oo & 31;
        const float v = (thr_s[t * 33 + k] > 0.0f && mask_s[k] > 0.0f) ? 1.0f : 0.0f;
        __builtin_nontemporal_store(v, out + (size_t)t * (KN * RFN) + k * RFN + r);
    }
}

extern "C" void kernel_launch(void* const* d_in, const int* in_sizes, int n_in,
                              void* d_out, int out_size, void* d_ws, size_t ws_size,
                              hipStream_t stream) {
    const float* rec = (const float*)d_in[0];   // rec_field (32,1,512,2048)
    const float* wgt = (const float*)d_in[1];   // W         (512,32,1,2048)
    // d_in[2] = reward: unused by the forward output; d_ws: unused (fully fused)
    float* out = (float*)d_out;                 // (32,1,32,512)
    column1_fused<<<dim3(RFN), dim3(512), 0, stream>>>(rec, wgt, out);
}